// Round 1
// baseline (317.093 us; speedup 1.0000x reference)
//
#include <hip/hip_runtime.h>

// Problem constants (B=32, T=4096, D=256, A=128, window=64)
#define TT 4096
#define DD 256
#define AA 128
#define WIN 64

typedef short bf16x8 __attribute__((ext_vector_type(8)));
typedef float f32x4 __attribute__((ext_vector_type(4)));

__device__ __forceinline__ unsigned short f2bf(float f) {
    unsigned int u = __builtin_bit_cast(unsigned int, f);
    u += 0x7FFFu + ((u >> 16) & 1u);   // RTNE
    return (unsigned short)(u >> 16);
}

// ---------------- prep: Wp fp32 -> bf16 (64 KiB, L2-resident) ----------------
__global__ __launch_bounds__(256) void prep_wp(const float* __restrict__ Wp,
                                               unsigned short* __restrict__ wpb) {
    int i = blockIdx.x * 256 + threadIdx.x;   // 32768 total
    wpb[i] = f2bf(Wp[i]);
}

// ---------------- gate: g = sigmoid(Wg . tanh(x Wp^T + bp)) ------------------
// Block = 256 thr (4 waves), 64 rows/block. MFMA 16x16x32 bf16.
#define ROWS 64
#define LDK 264   // 256 + 8 pad (elements) -> row stride 528 B, 16B-aligned

__global__ __launch_bounds__(256) void gate_kernel(
        const float* __restrict__ x, const unsigned short* __restrict__ wpb,
        const float* __restrict__ bp, const float* __restrict__ Wg,
        float* __restrict__ g) {
    __shared__ unsigned short xs[ROWS * LDK];
    const int tid = threadIdx.x;
    const long row0 = (long)blockIdx.x * ROWS;

    // stage x tile (64 rows x 256) fp32 -> bf16 LDS
#pragma unroll
    for (int it = 0; it < 16; ++it) {
        int idx = it * 256 + tid;          // 4096 float4 groups
        int r   = idx >> 6;                // 64 groups per row
        int c4  = idx & 63;
        float4 v = reinterpret_cast<const float4*>(x + (row0 + r) * DD)[c4];
        ushort4 h;
        h.x = f2bf(v.x); h.y = f2bf(v.y); h.z = f2bf(v.z); h.w = f2bf(v.w);
        *reinterpret_cast<ushort4*>(&xs[r * LDK + c4 * 4]) = h;
    }
    __syncthreads();

    const int lane = tid & 63;
    const int wave = tid >> 6;
    const int quad = lane >> 4;
    const int nrow = lane & 15;

    f32x4 acc[8];
#pragma unroll
    for (int nt = 0; nt < 8; ++nt) acc[nt] = (f32x4){0.f, 0.f, 0.f, 0.f};

    const unsigned short* xbase = &xs[(wave * 16 + nrow) * LDK + quad * 8];
#pragma unroll
    for (int k0 = 0; k0 < 8; ++k0) {               // K = 256 = 8 x 32
        bf16x8 afrag = *reinterpret_cast<const bf16x8*>(xbase + k0 * 32);
#pragma unroll
        for (int nt = 0; nt < 8; ++nt) {           // N = 128 = 8 x 16
            bf16x8 bfrag = *reinterpret_cast<const bf16x8*>(
                wpb + (nt * 16 + nrow) * DD + k0 * 32 + quad * 8);
            acc[nt] = __builtin_amdgcn_mfma_f32_16x16x32_bf16(afrag, bfrag, acc[nt], 0, 0, 0);
        }
    }

    // epilogue: tanh, * Wg, row-reduce over n (16 lanes x 8 tiles), sigmoid
    float rowsum[4] = {0.f, 0.f, 0.f, 0.f};
#pragma unroll
    for (int nt = 0; nt < 8; ++nt) {
        int n = nt * 16 + nrow;
        float wg = Wg[n];
        float bv = bp[n];
#pragma unroll
        for (int r = 0; r < 4; ++r) {
            float pre = acc[nt][r] + bv;
            float e = __expf(2.0f * pre);
            float th = 1.0f - 2.0f / (e + 1.0f);   // tanh, saturates correctly
            rowsum[r] += th * wg;
        }
    }
#pragma unroll
    for (int off = 1; off <= 8; off <<= 1) {
#pragma unroll
        for (int r = 0; r < 4; ++r)
            rowsum[r] += __shfl_xor(rowsum[r], off, 64);
    }
    if (nrow == 0) {
#pragma unroll
        for (int r = 0; r < 4; ++r) {
            long row = row0 + wave * 16 + quad * 4 + r;   // C-layout: row = quad*4+reg
            float s = rowsum[r];
            g[row] = 1.0f / (1.0f + __expf(-s));
        }
    }
}

// ---------------- den: inv_den[b,t] = 1 / sum_{s=max(t-63,0)}^{t} g[b,s] -----
__global__ __launch_bounds__(256) void den_kernel(const float* __restrict__ g,
                                                  float* __restrict__ invden) {
    int idx = blockIdx.x * 256 + threadIdx.x;   // 131072
    int t = idx & (TT - 1);
    const float* gb = g + (idx - t);
    int lo = t - (WIN - 1); if (lo < 0) lo = 0;
    float s = 0.f;
    for (int u = lo; u <= t; ++u) s += gb[u];
    invden[idx] = 1.0f / s;
}

// ---------------- stream: sliding-window sum of g*x, scaled by inv_den ------
// grid: 32 b x 16 chunks of 256 t. One thread per d column; LDS ring [i][d].
#define TC 256
#define NCHUNK 16

__global__ __launch_bounds__(256) void stream_kernel(
        const float* __restrict__ x, const float* __restrict__ g,
        const float* __restrict__ invden, float* __restrict__ out) {
    __shared__ float ring[WIN][DD];    // bank = d%32 -> conflict-free
    const int b = blockIdx.x >> 4;
    const int chunk = blockIdx.x & (NCHUNK - 1);
    const int t0 = chunk * TC;
    const int d = threadIdx.x;
    const float* xb = x + (size_t)b * TT * DD;
    const float* gb = g + (size_t)b * TT;
    const float* ivb = invden + (size_t)b * TT;
    float* ob = out + (size_t)b * TT * DD;

    float S = 0.f;
    // warmup halo: s in [t0-64, t0-1]; t0 % 64 == 0 so ring slot = i
#pragma unroll 8
    for (int i = 0; i < WIN; ++i) {
        int s = t0 - WIN + i;
        float v = 0.f;
        if (s >= 0) v = gb[s] * xb[(size_t)s * DD + d];
        ring[i][d] = v;
        S += v;
    }
    // main: S += v[t] - v[t-64]
#pragma unroll 8
    for (int tt = 0; tt < TC; ++tt) {
        int t = t0 + tt;
        int i = tt & (WIN - 1);
        float v = gb[t] * xb[(size_t)t * DD + d];
        S += v - ring[i][d];
        ring[i][d] = v;
        ob[(size_t)t * DD + d] = S * ivb[t];
    }
}

extern "C" void kernel_launch(void* const* d_in, const int* in_sizes, int n_in,
                              void* d_out, int out_size, void* d_ws, size_t ws_size,
                              hipStream_t stream) {
    const float* x  = (const float*)d_in[0];
    const float* Wp = (const float*)d_in[1];
    const float* bp = (const float*)d_in[2];
    const float* Wg = (const float*)d_in[3];
    float* out = (float*)d_out;

    // ws layout: [0,64K) Wp bf16 | [64K, 64K+512K) g | next 512K inv_den
    unsigned short* wpb = (unsigned short*)d_ws;
    float* g      = (float*)((char*)d_ws + 65536);
    float* invden = (float*)((char*)d_ws + 65536 + 524288);

    prep_wp<<<AA * DD / 256, 256, 0, stream>>>(Wp, wpb);
    gate_kernel<<<32 * TT / ROWS, 256, 0, stream>>>(x, wpb, bp, Wg, g);
    den_kernel<<<32 * TT / 256, 256, 0, stream>>>(g, invden);
    stream_kernel<<<32 * NCHUNK, 256, 0, stream>>>(x, g, invden, out);
}

// Round 2
// 310.653 us; speedup vs baseline: 1.0207x; 1.0207x over previous
//
#include <hip/hip_runtime.h>

// Problem constants (B=32, T=4096, D=256, A=128, window=64)
#define TT 4096
#define DD 256
#define AA 128
#define WIN 64

typedef short bf16x8 __attribute__((ext_vector_type(8)));
typedef float f32x4 __attribute__((ext_vector_type(4)));

__device__ __forceinline__ unsigned short f2bf(float f) {
    unsigned int u = __builtin_bit_cast(unsigned int, f);
    u += 0x7FFFu + ((u >> 16) & 1u);   // RTNE
    return (unsigned short)(u >> 16);
}

// ---------------- prep: Wp fp32 -> bf16 (64 KiB, L2-resident) ----------------
__global__ __launch_bounds__(256) void prep_wp(const float* __restrict__ Wp,
                                               unsigned short* __restrict__ wpb) {
    int i = blockIdx.x * 256 + threadIdx.x;   // 32768 total
    wpb[i] = f2bf(Wp[i]);
}

// ---------------- gate: g = sigmoid(Wg . tanh(x Wp^T + bp)) ------------------
// Block = 256 thr (4 waves). Each wave owns 32 n-cols (B in registers, loaded
// once). Block processes 128 rows as 2 subtiles of 64. MFMA 16x16x32 bf16.
#define LDK 264       // 256 + 8 pad (bf16 elems) -> row stride 528 B
#define RTILE 128
#define NSUB 2

__global__ __launch_bounds__(256, 3) void gate_kernel(
        const float* __restrict__ x, const unsigned short* __restrict__ wpb,
        const float* __restrict__ bp, const float* __restrict__ Wg,
        float* __restrict__ g) {
    __shared__ unsigned short xs[64 * LDK];
    __shared__ float psum[4][64];
    const int tid  = threadIdx.x;
    const int lane = tid & 63;
    const int wave = tid >> 6;
    const int quad = lane >> 4;
    const int nrow = lane & 15;
    const long row0 = (long)blockIdx.x * RTILE;

    // B fragments: wave covers n in [wave*32, wave*32+32), nt = 0..1
    bf16x8 bfrag[2][8];
    float bpv[2], wgv[2];
#pragma unroll
    for (int nt = 0; nt < 2; ++nt) {
        int n = wave * 32 + nt * 16 + nrow;
        bpv[nt] = bp[n];
        wgv[nt] = Wg[n];
#pragma unroll
        for (int k0 = 0; k0 < 8; ++k0)
            bfrag[nt][k0] = *reinterpret_cast<const bf16x8*>(
                wpb + n * DD + k0 * 32 + quad * 8);
    }

    for (int s = 0; s < NSUB; ++s) {
        const float* xsrc = x + (row0 + s * 64) * DD;
        // stage 64 rows x 256 k, fp32 -> bf16
#pragma unroll
        for (int it = 0; it < 16; ++it) {
            int idx = it * 256 + tid;      // 4096 float4 groups
            int r   = idx >> 6;
            int c4  = idx & 63;
            float4 v = reinterpret_cast<const float4*>(xsrc + r * DD)[c4];
            ushort4 h;
            h.x = f2bf(v.x); h.y = f2bf(v.y); h.z = f2bf(v.z); h.w = f2bf(v.w);
            *reinterpret_cast<ushort4*>(&xs[r * LDK + c4 * 4]) = h;
        }
        __syncthreads();

        f32x4 acc[4][2];
#pragma unroll
        for (int mt = 0; mt < 4; ++mt)
#pragma unroll
            for (int nt = 0; nt < 2; ++nt)
                acc[mt][nt] = (f32x4){0.f, 0.f, 0.f, 0.f};

#pragma unroll
        for (int k0 = 0; k0 < 8; ++k0) {
#pragma unroll
            for (int mt = 0; mt < 4; ++mt) {
                bf16x8 af = *reinterpret_cast<const bf16x8*>(
                    &xs[(mt * 16 + nrow) * LDK + quad * 8 + k0 * 32]);
                acc[mt][0] = __builtin_amdgcn_mfma_f32_16x16x32_bf16(af, bfrag[0][k0], acc[mt][0], 0, 0, 0);
                acc[mt][1] = __builtin_amdgcn_mfma_f32_16x16x32_bf16(af, bfrag[1][k0], acc[mt][1], 0, 0, 0);
            }
        }

        // epilogue: tanh -> *Wg -> partial row sums (this wave's 32 n-cols)
        float p[4][4];
#pragma unroll
        for (int mt = 0; mt < 4; ++mt)
#pragma unroll
            for (int r = 0; r < 4; ++r) p[mt][r] = 0.f;
#pragma unroll
        for (int nt = 0; nt < 2; ++nt) {
#pragma unroll
            for (int mt = 0; mt < 4; ++mt) {
#pragma unroll
                for (int r = 0; r < 4; ++r) {
                    float pre = acc[mt][nt][r] + bpv[nt];
                    float e  = __expf(2.0f * pre);
                    float th = 1.0f - 2.0f * __builtin_amdgcn_rcpf(e + 1.0f);
                    p[mt][r] += th * wgv[nt];
                }
            }
        }
        // reduce over the 16 nrow lanes (lane bits 0..3)
#pragma unroll
        for (int off = 1; off <= 8; off <<= 1)
#pragma unroll
            for (int mt = 0; mt < 4; ++mt)
#pragma unroll
                for (int r = 0; r < 4; ++r)
                    p[mt][r] += __shfl_xor(p[mt][r], off, 64);
        if (nrow == 0) {
#pragma unroll
            for (int mt = 0; mt < 4; ++mt)
#pragma unroll
                for (int r = 0; r < 4; ++r)
                    psum[wave][mt * 16 + quad * 4 + r] = p[mt][r];
        }
        __syncthreads();
        if (tid < 64) {
            float ssum = psum[0][tid] + psum[1][tid] + psum[2][tid] + psum[3][tid];
            g[row0 + s * 64 + tid] = __builtin_amdgcn_rcpf(1.0f + __expf(-ssum));
        }
        __syncthreads();   // protect xs/psum before next subtile
    }
}

// ---------------- stream: windowed sum of g*x over win=64, / windowed g-sum --
// Ring-less: S += g[t]x[t] - g[t-64]x[t-64]; the subtrahend re-read is L2/L3
// warm. den fused: per-thread scalar recurrence on staged g. TC=128 -> 1024
// blocks, ~1 KiB LDS, high occupancy.
#define TC 128
#define NCHUNK (TT / TC)   // 32

__global__ __launch_bounds__(256) void stream_kernel(
        const float* __restrict__ x, const float* __restrict__ g,
        float* __restrict__ out) {
    __shared__ float gbuf[TC + WIN];
    const int b     = blockIdx.x >> 5;          // NCHUNK = 32
    const int chunk = blockIdx.x & (NCHUNK - 1);
    const int t0    = chunk * TC;
    const int d     = threadIdx.x;
    const float* xb = x + (size_t)b * TT * DD;
    const float* gb = g + (size_t)b * TT;
    float* ob = out + (size_t)b * TT * DD;

    // stage g[t0-64 .. t0+TC-1], zero-padded below 0
    if (d < TC + WIN) {
        int s = t0 - WIN + d;
        gbuf[d] = (s >= 0) ? gb[s] : 0.f;
    }
    __syncthreads();

    // halo init over [t0-64, t0-1] (g=0 padding kills clamped loads)
    float S = 0.f, Sg = 0.f;
#pragma unroll 16
    for (int i = 0; i < WIN; ++i) {
        int s  = t0 - WIN + i;
        int sc = s < 0 ? 0 : s;
        float gv = gbuf[i];
        S  += gv * xb[(size_t)sc * DD + d];
        Sg += gv;
    }

#pragma unroll 8
    for (int tt = 0; tt < TC; ++tt) {
        int t  = t0 + tt;
        int ts = t - WIN;
        int tsc = ts < 0 ? 0 : ts;
        float gnew = gbuf[WIN + tt];
        float gold = gbuf[tt];
        float vnew = gnew * xb[(size_t)t * DD + d];
        float vold = gold * xb[(size_t)tsc * DD + d];
        S  += vnew - vold;
        Sg += gnew - gold;
        ob[(size_t)t * DD + d] = S * __builtin_amdgcn_rcpf(Sg);
    }
}

extern "C" void kernel_launch(void* const* d_in, const int* in_sizes, int n_in,
                              void* d_out, int out_size, void* d_ws, size_t ws_size,
                              hipStream_t stream) {
    const float* x  = (const float*)d_in[0];
    const float* Wp = (const float*)d_in[1];
    const float* bp = (const float*)d_in[2];
    const float* Wg = (const float*)d_in[3];
    float* out = (float*)d_out;

    // ws layout: [0,64K) Wp bf16 | [64K, 64K+512K) g
    unsigned short* wpb = (unsigned short*)d_ws;
    float* g = (float*)((char*)d_ws + 65536);

    prep_wp<<<AA * DD / 256, 256, 0, stream>>>(Wp, wpb);
    gate_kernel<<<32 * TT / RTILE, 256, 0, stream>>>(x, wpb, bp, Wg, g);
    stream_kernel<<<32 * NCHUNK, 256, 0, stream>>>(x, g, out);
}